// Round 8
// baseline (206.176 us; speedup 1.0000x reference)
//
#include <hip/hip_runtime.h>

#define IN_CH   128
#define HIDDEN  256
#define N_GRAPHS 64
#define GN 32  // nodes per gemm block

// deg count + per-edge rank within its dst bucket (the same atomic does both)
__global__ void k_deg(const int* __restrict__ dst, int* __restrict__ deg,
                      int* __restrict__ rank, int e) {
  int i = blockIdx.x * blockDim.x + threadIdx.x;
  if (i < e) rank[i] = atomicAdd(&deg[dst[i]], 1);
}

__global__ __launch_bounds__(1024) void k_scan1(const int* __restrict__ deg,
    int* __restrict__ offs, int* __restrict__ bsum, int n) {
  __shared__ int sm[1024];
  int t = threadIdx.x;
  int i = blockIdx.x * 1024 + t;
  int v = (i < n) ? deg[i] : 0;
  sm[t] = v;
  __syncthreads();
  for (int d = 1; d < 1024; d <<= 1) {
    int add = (t >= d) ? sm[t - d] : 0;
    __syncthreads();
    sm[t] += add;
    __syncthreads();
  }
  if (i < n) offs[i] = sm[t] - v;  // exclusive
  if (t == 1023) bsum[blockIdx.x] = sm[1023];
}

// single-wave shfl scan (nb <= 64)
__global__ void k_scan2(const int* __restrict__ bsum, int* __restrict__ bofs, int nb) {
  int t = threadIdx.x;
  int orig = (t < nb) ? bsum[t] : 0;
  int v = orig;
  for (int d = 1; d < 64; d <<= 1) {
    int u = __shfl_up(v, d, 64);
    if (t >= d) v += u;
  }
  if (t < nb) bofs[t] = v - orig;  // exclusive
}

// offs += block offset; dinv = 1/sqrt(deg+1)
__global__ void k_scan3(int* __restrict__ offs, const int* __restrict__ bofs,
                        const int* __restrict__ deg, float* __restrict__ dinv, int n) {
  int i = blockIdx.x * blockDim.x + threadIdx.x;
  if (i < n) {
    offs[i] += bofs[i >> 10];
    dinv[i] = 1.0f / sqrtf((float)(deg[i] + 1));
  }
}

// atomic-free CSR fill using precomputed ranks
__global__ void k_place(const int* __restrict__ src, const int* __restrict__ dst,
                        const int* __restrict__ rank, const int* __restrict__ offs,
                        int* __restrict__ csr, int e) {
  int i = blockIdx.x * blockDim.x + threadIdx.x;
  if (i < e) csr[offs[dst[i]] + rank[i]] = src[i];
}

// 4 nodes/block, high occupancy (0 LDS, low VGPR). lane = es*16+cg;
// es = edge slot (4), cg = channel group (16 x 8 floats). 8 rows in flight.
__global__ __launch_bounds__(256) void k_agg(const float* __restrict__ x,
    const int* __restrict__ csr, const int* __restrict__ offs,
    const int* __restrict__ degc, const float* __restrict__ dinv,
    float* __restrict__ y, int n) {
  int node = blockIdx.x * 4 + (threadIdx.x >> 6);
  if (node >= n) return;
  int lane = threadIdx.x & 63;
  int es = lane >> 4;
  int cg = lane & 15;
  int o = offs[node], c = degc[node];
  float4 A0 = {0.f,0.f,0.f,0.f}, A1 = {0.f,0.f,0.f,0.f};
  int ii = es;
  for (; ii + 4 < c; ii += 8) {
    int s0 = csr[o + ii];
    int s1 = csr[o + ii + 4];
    float w0 = dinv[s0];
    float w1 = dinv[s1];
    const float4* r0 = reinterpret_cast<const float4*>(&x[(size_t)s0 * IN_CH + cg * 8]);
    const float4* r1 = reinterpret_cast<const float4*>(&x[(size_t)s1 * IN_CH + cg * 8]);
    float4 a0 = r0[0], b0 = r0[1];
    float4 a1 = r1[0], b1 = r1[1];
    A0.x += w0 * a0.x; A0.y += w0 * a0.y; A0.z += w0 * a0.z; A0.w += w0 * a0.w;
    A1.x += w0 * b0.x; A1.y += w0 * b0.y; A1.z += w0 * b0.z; A1.w += w0 * b0.w;
    A0.x += w1 * a1.x; A0.y += w1 * a1.y; A0.z += w1 * a1.z; A0.w += w1 * a1.w;
    A1.x += w1 * b1.x; A1.y += w1 * b1.y; A1.z += w1 * b1.z; A1.w += w1 * b1.w;
  }
  if (ii < c) {
    int s0 = csr[o + ii];
    float w0 = dinv[s0];
    const float4* r0 = reinterpret_cast<const float4*>(&x[(size_t)s0 * IN_CH + cg * 8]);
    float4 a0 = r0[0], b0 = r0[1];
    A0.x += w0 * a0.x; A0.y += w0 * a0.y; A0.z += w0 * a0.z; A0.w += w0 * a0.w;
    A1.x += w0 * b0.x; A1.y += w0 * b0.y; A1.z += w0 * b0.z; A1.w += w0 * b0.w;
  }
  float v[8] = {A0.x, A0.y, A0.z, A0.w, A1.x, A1.y, A1.z, A1.w};
#pragma unroll
  for (int k = 0; k < 8; ++k) {
    v[k] += __shfl_xor(v[k], 16, 64);
    v[k] += __shfl_xor(v[k], 32, 64);
  }
  if (es == 0) {
    float dn = dinv[node];
    const float4* xr = reinterpret_cast<const float4*>(&x[(size_t)node * IN_CH + cg * 8]);
    float4 xa = xr[0], xb = xr[1];
    float4 o0, o1;
    o0.x = (v[0] + xa.x * dn) * dn;
    o0.y = (v[1] + xa.y * dn) * dn;
    o0.z = (v[2] + xa.z * dn) * dn;
    o0.w = (v[3] + xa.w * dn) * dn;
    o1.x = (v[4] + xb.x * dn) * dn;
    o1.y = (v[5] + xb.y * dn) * dn;
    o1.z = (v[6] + xb.z * dn) * dn;
    o1.w = (v[7] + xb.w * dn) * dn;
    float4* yr = reinterpret_cast<float4*>(&y[(size_t)node * IN_CH + cg * 8]);
    yr[0] = o0;
    yr[1] = o1;
  }
}

// GEMM(128->256)+bias+relu fused with per-graph pooling. 32 nodes/block,
// 256 threads, thread tile 4 nodes x 8 channels. w1 streamed from L2 with
// register prefetch; small LDS footprint -> ~6 blocks/CU for latency hiding.
__global__ __launch_bounds__(256) void k_gemmpool(
    const float* __restrict__ y, const float* __restrict__ w1,
    const float* __restrict__ b1, const int* __restrict__ batch,
    float* __restrict__ pooled, int n) {
  __shared__ float ylds[GN * 128];   // 16 KB
  __shared__ float part[4][HIDDEN];  // 4 KB
  __shared__ int bl[GN];
  int t = threadIdx.x;
  int node0 = blockIdx.x * GN;

  if (t < GN) {
    int nd = node0 + t;
    bl[t] = (nd < n) ? batch[nd] : -1;
  }
  {
    float* pp = &part[0][0];
    for (int i = t; i < 4 * HIDDEN; i += 256) pp[i] = 0.f;
  }
  {
    const float4* ys = reinterpret_cast<const float4*>(y);
    float4* yd = reinterpret_cast<float4*>(ylds);
    int base4 = node0 * 32, tot4 = n * 32;
#pragma unroll
    for (int i = 0; i < (GN * 32) / 256; ++i) {
      int idx = t + i * 256;
      int g = base4 + idx;
      float4 v = {0.f, 0.f, 0.f, 0.f};
      if (g < tot4) v = ys[g];
      yd[idx] = v;
    }
  }
  __syncthreads();  // the only barrier before the pooling epilogue

  int cg2 = t & 31, ng = t >> 5;
  float acc[4][8];
#pragma unroll
  for (int m = 0; m < 4; ++m)
#pragma unroll
    for (int c = 0; c < 8; ++c) acc[m][c] = 0.f;

  const float4* wg = reinterpret_cast<const float4*>(w1);  // [k][64 float4]
  float4 wv0[4], wv1[4];
#pragma unroll
  for (int u = 0; u < 4; ++u) {
    wv0[u] = wg[u * 64 + cg2];
    wv1[u] = wg[u * 64 + 32 + cg2];
  }
  for (int k4 = 0; k4 < 32; ++k4) {
    float4 nv0[4], nv1[4];
    if (k4 < 31) {
      const float4* wn = wg + (k4 + 1) * 4 * 64;
#pragma unroll
      for (int u = 0; u < 4; ++u) {
        nv0[u] = wn[u * 64 + cg2];
        nv1[u] = wn[u * 64 + 32 + cg2];
      }
    }
    int k = k4 * 4;
#pragma unroll
    for (int m = 0; m < 4; ++m) {
      float4 yv = *reinterpret_cast<const float4*>(&ylds[(ng * 4 + m) * 128 + k]);
      float ya[4] = {yv.x, yv.y, yv.z, yv.w};
#pragma unroll
      for (int u = 0; u < 4; ++u) {
        acc[m][0] += ya[u] * wv0[u].x;
        acc[m][1] += ya[u] * wv0[u].y;
        acc[m][2] += ya[u] * wv0[u].z;
        acc[m][3] += ya[u] * wv0[u].w;
        acc[m][4] += ya[u] * wv1[u].x;
        acc[m][5] += ya[u] * wv1[u].y;
        acc[m][6] += ya[u] * wv1[u].z;
        acc[m][7] += ya[u] * wv1[u].w;
      }
    }
    if (k4 < 31) {
#pragma unroll
      for (int u = 0; u < 4; ++u) { wv0[u] = nv0[u]; wv1[u] = nv1[u]; }
    }
  }

  // relu + per-graph pooled sums (batch sorted => runs)
  float b0[4], b4[4];
#pragma unroll
  for (int u = 0; u < 4; ++u) { b0[u] = b1[cg2 * 4 + u]; b4[u] = b1[128 + cg2 * 4 + u]; }
  int g0 = bl[0];
  float s[8];
#pragma unroll
  for (int u = 0; u < 8; ++u) s[u] = 0.f;
  int gcur = -1;

  auto flush = [&](int g) {
    if (g < 0) return;
    int gi = g - g0;
    if (gi < 4) {
#pragma unroll
      for (int u = 0; u < 4; ++u) {
        atomicAdd(&part[gi][cg2 * 4 + u], s[u]);
        atomicAdd(&part[gi][128 + cg2 * 4 + u], s[4 + u]);
      }
    } else {
#pragma unroll
      for (int u = 0; u < 4; ++u) {
        atomicAdd(&pooled[g * HIDDEN + cg2 * 4 + u], s[u]);
        atomicAdd(&pooled[g * HIDDEN + 128 + cg2 * 4 + u], s[4 + u]);
      }
    }
  };

#pragma unroll
  for (int m = 0; m < 4; ++m) {
    int row = ng * 4 + m;
    int node = node0 + row;
    int g = (node < n) ? bl[row] : -1;
    if (g != gcur) {
      flush(gcur);
#pragma unroll
      for (int u = 0; u < 8; ++u) s[u] = 0.f;
      gcur = g;
    }
    if (g >= 0) {
      s[0] += fmaxf(acc[m][0] + b0[0], 0.f);
      s[1] += fmaxf(acc[m][1] + b0[1], 0.f);
      s[2] += fmaxf(acc[m][2] + b0[2], 0.f);
      s[3] += fmaxf(acc[m][3] + b0[3], 0.f);
      s[4] += fmaxf(acc[m][4] + b4[0], 0.f);
      s[5] += fmaxf(acc[m][5] + b4[1], 0.f);
      s[6] += fmaxf(acc[m][6] + b4[2], 0.f);
      s[7] += fmaxf(acc[m][7] + b4[3], 0.f);
    }
  }
  flush(gcur);

  __syncthreads();
  int lastIdx = min(GN, n - node0) - 1;
  int gmax = bl[lastIdx];
  int span = gmax - g0;
  if (span > 3) span = 3;
  for (int gi = 0; gi <= span; ++gi) {
    if (t < HIDDEN) atomicAdd(&pooled[(g0 + gi) * HIDDEN + t], part[gi][t]);
  }
}

// One block per graph: cnt via binary search (batch sorted), mean,
// z = relu(p@w2+b2), out = z@w3+b3
__global__ __launch_bounds__(256) void k_head(const float* __restrict__ pooled,
    const int* __restrict__ batch, int n, const float* __restrict__ w2,
    const float* __restrict__ b2, const float* __restrict__ w3,
    const float* __restrict__ b3, float* __restrict__ out) {
  __shared__ float p[256];
  __shared__ float red[4];
  __shared__ int scnt;
  int g = blockIdx.x, t = threadIdx.x;
  if (t == 0) {
    int lo = 0, hi = n;
    while (lo < hi) { int mid = (lo + hi) >> 1; if (batch[mid] < g) lo = mid + 1; else hi = mid; }
    int a = lo;
    lo = 0; hi = n;
    int g1 = g + 1;
    while (lo < hi) { int mid = (lo + hi) >> 1; if (batch[mid] < g1) lo = mid + 1; else hi = mid; }
    scnt = lo - a;
  }
  __syncthreads();
  float c = (float)max(scnt, 1);
  p[t] = pooled[g * HIDDEN + t] / c;
  __syncthreads();
  float a = 0.f;
  for (int k = 0; k < 256; ++k) a += p[k] * w2[k * 256 + t];
  a += b2[t];
  a = fmaxf(a, 0.f);
  float part = a * w3[t];
  for (int off = 32; off > 0; off >>= 1) part += __shfl_down(part, off, 64);
  if ((t & 63) == 0) red[t >> 6] = part;
  __syncthreads();
  if (t == 0) out[g] = red[0] + red[1] + red[2] + red[3] + b3[0];
}

extern "C" void kernel_launch(void* const* d_in, const int* in_sizes, int n_in,
                              void* d_out, int out_size, void* d_ws, size_t ws_size,
                              hipStream_t stream) {
  const float* x    = (const float*)d_in[0];
  const int*   ei   = (const int*)d_in[1];
  const int*   batch= (const int*)d_in[2];
  const float* w1   = (const float*)d_in[3];
  const float* b1   = (const float*)d_in[4];
  const float* w2   = (const float*)d_in[5];
  const float* b2   = (const float*)d_in[6];
  const float* w3   = (const float*)d_in[7];
  const float* b3   = (const float*)d_in[8];
  float* out = (float*)d_out;

  int N = in_sizes[2];
  int E = in_sizes[1] / 2;
  const int* esrc = ei;
  const int* edst = ei + E;

  // layout: [deg_i N][pooled 16384] (one zero-fill) [offs N][dinv N][bsum 64]
  //         [bofs 64][rank E][csr E][yb N*128]
  int* W = (int*)d_ws;
  int*   deg_i  = W;
  float* pooled = (float*)(W + N);
  int*   offs   = W + N + N_GRAPHS * HIDDEN;
  float* dinv   = (float*)(offs + N);
  int*   bsum   = (int*)(dinv + N);
  int*   bofs   = bsum + 64;
  int*   rank   = bofs + 64;
  int*   csr    = rank + E;
  float* yb     = (float*)(csr + E);

  hipMemsetAsync(deg_i, 0, (size_t)(N + N_GRAPHS * HIDDEN) * sizeof(int), stream);

  const int tb = 256;
  k_deg<<<(E + tb - 1) / tb, tb, 0, stream>>>(edst, deg_i, rank, E);
  int nb = (N + 1023) / 1024;
  k_scan1<<<nb, 1024, 0, stream>>>(deg_i, offs, bsum, N);
  k_scan2<<<1, 64, 0, stream>>>(bsum, bofs, nb);
  k_scan3<<<(N + tb - 1) / tb, tb, 0, stream>>>(offs, bofs, deg_i, dinv, N);
  k_place<<<(E + tb - 1) / tb, tb, 0, stream>>>(esrc, edst, rank, offs, csr, E);
  k_agg<<<(N + 3) / 4, 256, 0, stream>>>(x, csr, offs, deg_i, dinv, yb, N);
  k_gemmpool<<<(N + GN - 1) / GN, 256, 0, stream>>>(yb, w1, b1, batch, pooled, N);
  k_head<<<N_GRAPHS, 256, 0, stream>>>(pooled, batch, N, w2, b2, w3, b3, out);
}

// Round 9
// 158.788 us; speedup vs baseline: 1.2984x; 1.2984x over previous
//
#include <hip/hip_runtime.h>

#define IN_CH   128
#define HIDDEN  256
#define N_GRAPHS 64
#define GN 64  // nodes per gemm block

typedef short short8 __attribute__((ext_vector_type(8)));
typedef float f32x4 __attribute__((ext_vector_type(4)));

__device__ inline unsigned f2bf(float f) {
  unsigned u = __float_as_uint(f);
  return (u + 0x7fffu + ((u >> 16) & 1u)) >> 16;
}
__device__ inline unsigned pack2(float lo, float hi) {
  return (f2bf(hi) << 16) | f2bf(lo);
}
__device__ inline void acc8(uint4 v, float w, float* A) {
  A[0] += w * __uint_as_float(v.x << 16);
  A[1] += w * __uint_as_float(v.x & 0xffff0000u);
  A[2] += w * __uint_as_float(v.y << 16);
  A[3] += w * __uint_as_float(v.y & 0xffff0000u);
  A[4] += w * __uint_as_float(v.z << 16);
  A[5] += w * __uint_as_float(v.z & 0xffff0000u);
  A[6] += w * __uint_as_float(v.w << 16);
  A[7] += w * __uint_as_float(v.w & 0xffff0000u);
}

// x (f32) -> xh (bf16), 8 elements/thread
__global__ void k_cast_x(const float* __restrict__ x, ushort* __restrict__ xh, int total8) {
  int i = blockIdx.x * blockDim.x + threadIdx.x;
  if (i >= total8) return;
  const float4* xp = reinterpret_cast<const float4*>(x) + (size_t)i * 2;
  float4 a = xp[0], b = xp[1];
  uint4 o;
  o.x = pack2(a.x, a.y);
  o.y = pack2(a.z, a.w);
  o.z = pack2(b.x, b.y);
  o.w = pack2(b.z, b.w);
  reinterpret_cast<uint4*>(xh)[i] = o;
}

// w1 [128][256] f32 -> w1t [256][128] bf16
__global__ void k_cast_w1t(const float* __restrict__ w1, ushort* __restrict__ w1t) {
  int idx = blockIdx.x * blockDim.x + threadIdx.x;  // 32768
  int nn = idx >> 7, k = idx & 127;
  w1t[idx] = (ushort)f2bf(w1[k * 256 + nn]);
}

// deg count + per-edge rank within its dst bucket (the same atomic does both)
__global__ void k_deg(const int* __restrict__ dst, int* __restrict__ deg,
                      int* __restrict__ rank, int e) {
  int i = blockIdx.x * blockDim.x + threadIdx.x;
  if (i < e) rank[i] = atomicAdd(&deg[dst[i]], 1);
}

__global__ __launch_bounds__(1024) void k_scan1(const int* __restrict__ deg,
    int* __restrict__ offs, int* __restrict__ bsum, int n) {
  __shared__ int sm[1024];
  int t = threadIdx.x;
  int i = blockIdx.x * 1024 + t;
  int v = (i < n) ? deg[i] : 0;
  sm[t] = v;
  __syncthreads();
  for (int d = 1; d < 1024; d <<= 1) {
    int add = (t >= d) ? sm[t - d] : 0;
    __syncthreads();
    sm[t] += add;
    __syncthreads();
  }
  if (i < n) offs[i] = sm[t] - v;  // exclusive
  if (t == 1023) bsum[blockIdx.x] = sm[1023];
}

// single-wave shfl scan (nb <= 64)
__global__ void k_scan2(const int* __restrict__ bsum, int* __restrict__ bofs, int nb) {
  int t = threadIdx.x;
  int orig = (t < nb) ? bsum[t] : 0;
  int v = orig;
  for (int d = 1; d < 64; d <<= 1) {
    int u = __shfl_up(v, d, 64);
    if (t >= d) v += u;
  }
  if (t < nb) bofs[t] = v - orig;  // exclusive
}

// offs += block offset; dinv = 1/sqrt(deg+1)
__global__ void k_scan3(int* __restrict__ offs, const int* __restrict__ bofs,
                        const int* __restrict__ deg, float* __restrict__ dinv, int n) {
  int i = blockIdx.x * blockDim.x + threadIdx.x;
  if (i < n) {
    offs[i] += bofs[i >> 10];
    dinv[i] = 1.0f / sqrtf((float)(deg[i] + 1));
  }
}

// atomic-free CSR fill using precomputed ranks
__global__ void k_place(const int* __restrict__ src, const int* __restrict__ dst,
                        const int* __restrict__ rank, const int* __restrict__ offs,
                        int* __restrict__ csr, int e) {
  int i = blockIdx.x * blockDim.x + threadIdx.x;
  if (i < e) csr[offs[dst[i]] + rank[i]] = src[i];
}

// 4 nodes/block. lane = es*16+cg; es = edge slot (4), cg = channel group
// (16 x 8 bf16 = 16B). 8 gather rows in flight; bf16 rows halve HBM traffic.
__global__ __launch_bounds__(256) void k_agg(const ushort* __restrict__ xh,
    const int* __restrict__ csr, const int* __restrict__ offs,
    const int* __restrict__ degc, const float* __restrict__ dinv,
    ushort* __restrict__ yh, int n) {
  int node = blockIdx.x * 4 + (threadIdx.x >> 6);
  if (node >= n) return;
  int lane = threadIdx.x & 63;
  int es = lane >> 4;
  int cg = lane & 15;
  int o = offs[node], c = degc[node];
  float A[8] = {0.f, 0.f, 0.f, 0.f, 0.f, 0.f, 0.f, 0.f};
  int ii = es;
  for (; ii + 4 < c; ii += 8) {
    int s0 = csr[o + ii];
    int s1 = csr[o + ii + 4];
    float w0 = dinv[s0];
    float w1 = dinv[s1];
    uint4 v0 = *reinterpret_cast<const uint4*>(&xh[(size_t)s0 * IN_CH + cg * 8]);
    uint4 v1 = *reinterpret_cast<const uint4*>(&xh[(size_t)s1 * IN_CH + cg * 8]);
    acc8(v0, w0, A);
    acc8(v1, w1, A);
  }
  if (ii < c) {
    int s0 = csr[o + ii];
    float w0 = dinv[s0];
    uint4 v0 = *reinterpret_cast<const uint4*>(&xh[(size_t)s0 * IN_CH + cg * 8]);
    acc8(v0, w0, A);
  }
#pragma unroll
  for (int k = 0; k < 8; ++k) {
    A[k] += __shfl_xor(A[k], 16, 64);
    A[k] += __shfl_xor(A[k], 32, 64);
  }
  if (es == 0) {
    float dn = dinv[node];
    uint4 xs = *reinterpret_cast<const uint4*>(&xh[(size_t)node * IN_CH + cg * 8]);
    float xv[8] = {0.f, 0.f, 0.f, 0.f, 0.f, 0.f, 0.f, 0.f};
    acc8(xs, dn, xv);  // xv = x_self * dn
    float v[8];
#pragma unroll
    for (int k = 0; k < 8; ++k) v[k] = (A[k] + xv[k]) * dn;
    uint4 w;
    w.x = pack2(v[0], v[1]);
    w.y = pack2(v[2], v[3]);
    w.z = pack2(v[4], v[5]);
    w.w = pack2(v[6], v[7]);
    *reinterpret_cast<uint4*>(&yh[(size_t)node * IN_CH + cg * 8]) = w;
  }
}

// MFMA GEMM(128->256 bf16)+bias+relu fused with per-graph pooling.
// 256 threads = 4 waves; wave w owns hidden cols [w*64, w*64+64).
// Per wave: 4x4 tiles of 16x16, K = 4 chunks of 32. No operand LDS.
__global__ __launch_bounds__(256) void k_gemmpool(
    const ushort* __restrict__ yh, const ushort* __restrict__ w1t,
    const float* __restrict__ b1, const int* __restrict__ batch,
    float* __restrict__ pooled, int n) {
  __shared__ float part[4][HIDDEN];  // 4 KB
  __shared__ int bl[GN];
  int t = threadIdx.x;
  int node0 = blockIdx.x * GN;

  if (t < GN) {
    int nd = node0 + t;
    bl[t] = (nd < n) ? batch[nd] : -1;
  }
  {
    float* pp = &part[0][0];
    for (int i = t; i < 4 * HIDDEN; i += 256) pp[i] = 0.f;
  }

  int wv = t >> 6, l = t & 63;
  int lr = l & 15;   // A-row / B-col / D-col index within tile
  int lk = l >> 4;   // k-slot (A/B), row-group (D)
  int colbase = wv * 64;

  f32x4 acc[4][4];
#pragma unroll
  for (int m = 0; m < 4; ++m)
#pragma unroll
    for (int nn = 0; nn < 4; ++nn) acc[m][nn] = (f32x4){0.f, 0.f, 0.f, 0.f};

#pragma unroll
  for (int kc = 0; kc < 4; ++kc) {
    short8 a[4], b[4];
#pragma unroll
    for (int m = 0; m < 4; ++m)
      a[m] = *reinterpret_cast<const short8*>(
          &yh[(size_t)(node0 + m * 16 + lr) * IN_CH + kc * 32 + lk * 8]);
#pragma unroll
    for (int nn = 0; nn < 4; ++nn)
      b[nn] = *reinterpret_cast<const short8*>(
          &w1t[(size_t)(colbase + nn * 16 + lr) * IN_CH + kc * 32 + lk * 8]);
#pragma unroll
    for (int m = 0; m < 4; ++m)
#pragma unroll
      for (int nn = 0; nn < 4; ++nn)
        acc[m][nn] = __builtin_amdgcn_mfma_f32_16x16x32_bf16(a[m], b[nn], acc[m][nn], 0, 0, 0);
  }

  __syncthreads();  // bl + part ready; mfma results in regs

  float bias[4];
#pragma unroll
  for (int nn = 0; nn < 4; ++nn) bias[nn] = b1[colbase + nn * 16 + lr];
  int g0 = bl[0];

#pragma unroll
  for (int m = 0; m < 4; ++m) {
    float s[4] = {0.f, 0.f, 0.f, 0.f};
    int gcur = -1;
#pragma unroll
    for (int j = 0; j < 4; ++j) {
      int row = m * 16 + lk * 4 + j;
      int node = node0 + row;
      int g = (node < n) ? bl[row] : -1;
      if (g != gcur) {
        if (gcur >= 0) {
          int gi = gcur - g0;
          if (gi < 4) {
#pragma unroll
            for (int nn = 0; nn < 4; ++nn)
              atomicAdd(&part[gi][colbase + nn * 16 + lr], s[nn]);
          } else {
#pragma unroll
            for (int nn = 0; nn < 4; ++nn)
              atomicAdd(&pooled[gcur * HIDDEN + colbase + nn * 16 + lr], s[nn]);
          }
        }
#pragma unroll
        for (int u = 0; u < 4; ++u) s[u] = 0.f;
        gcur = g;
      }
      if (g >= 0) {
#pragma unroll
        for (int nn = 0; nn < 4; ++nn)
          s[nn] += fmaxf(acc[m][nn][j] + bias[nn], 0.f);
      }
    }
    if (gcur >= 0) {
      int gi = gcur - g0;
      if (gi < 4) {
#pragma unroll
        for (int nn = 0; nn < 4; ++nn)
          atomicAdd(&part[gi][colbase + nn * 16 + lr], s[nn]);
      } else {
#pragma unroll
        for (int nn = 0; nn < 4; ++nn)
          atomicAdd(&pooled[gcur * HIDDEN + colbase + nn * 16 + lr], s[nn]);
      }
    }
  }

  __syncthreads();
  int lastIdx = min(GN, n - node0) - 1;
  int gmax = bl[lastIdx];
  int span = gmax - g0;
  if (span > 3) span = 3;
  for (int gi = 0; gi <= span; ++gi) {
    atomicAdd(&pooled[(g0 + gi) * HIDDEN + t], part[gi][t]);
  }
}

// One block per graph: cnt via binary search (batch sorted), mean,
// z = relu(p@w2+b2), out = z@w3+b3  (all fp32)
__global__ __launch_bounds__(256) void k_head(const float* __restrict__ pooled,
    const int* __restrict__ batch, int n, const float* __restrict__ w2,
    const float* __restrict__ b2, const float* __restrict__ w3,
    const float* __restrict__ b3, float* __restrict__ out) {
  __shared__ float p[256];
  __shared__ float red[4];
  __shared__ int scnt;
  int g = blockIdx.x, t = threadIdx.x;
  if (t == 0) {
    int lo = 0, hi = n;
    while (lo < hi) { int mid = (lo + hi) >> 1; if (batch[mid] < g) lo = mid + 1; else hi = mid; }
    int a = lo;
    lo = 0; hi = n;
    int g1 = g + 1;
    while (lo < hi) { int mid = (lo + hi) >> 1; if (batch[mid] < g1) lo = mid + 1; else hi = mid; }
    scnt = lo - a;
  }
  __syncthreads();
  float c = (float)max(scnt, 1);
  p[t] = pooled[g * HIDDEN + t] / c;
  __syncthreads();
  float a = 0.f;
  for (int k = 0; k < 256; ++k) a += p[k] * w2[k * 256 + t];
  a += b2[t];
  a = fmaxf(a, 0.f);
  float part = a * w3[t];
  for (int off = 32; off > 0; off >>= 1) part += __shfl_down(part, off, 64);
  if ((t & 63) == 0) red[t >> 6] = part;
  __syncthreads();
  if (t == 0) out[g] = red[0] + red[1] + red[2] + red[3] + b3[0];
}

extern "C" void kernel_launch(void* const* d_in, const int* in_sizes, int n_in,
                              void* d_out, int out_size, void* d_ws, size_t ws_size,
                              hipStream_t stream) {
  const float* x    = (const float*)d_in[0];
  const int*   ei   = (const int*)d_in[1];
  const int*   batch= (const int*)d_in[2];
  const float* w1   = (const float*)d_in[3];
  const float* b1   = (const float*)d_in[4];
  const float* w2   = (const float*)d_in[5];
  const float* b2   = (const float*)d_in[6];
  const float* w3   = (const float*)d_in[7];
  const float* b3   = (const float*)d_in[8];
  float* out = (float*)d_out;

  int N = in_sizes[2];
  int E = in_sizes[1] / 2;
  const int* esrc = ei;
  const int* edst = ei + E;
  int NP = ((N + 63) / 64) * 64;  // padded rows for yh

  // layout (ints): [deg_i N][pooled 16384] (one zero-fill) [offs N][dinv N]
  // [bsum 64][bofs 64][rank E][csr E][w1t 16384][xh N*64][yh NP*64]
  int* W = (int*)d_ws;
  int*    deg_i  = W;
  float*  pooled = (float*)(W + N);
  int*    offs   = W + N + N_GRAPHS * HIDDEN;
  float*  dinv   = (float*)(offs + N);
  int*    bsum   = (int*)(dinv + N);
  int*    bofs   = bsum + 64;
  int*    rank   = bofs + 64;
  int*    csr    = rank + E;
  ushort* w1t    = (ushort*)(csr + E);
  ushort* xh     = (ushort*)(csr + E + 16384);
  ushort* yh     = xh + (size_t)N * IN_CH;

  hipMemsetAsync(deg_i, 0, (size_t)(N + N_GRAPHS * HIDDEN) * sizeof(int), stream);

  const int tb = 256;
  k_cast_x<<<(N * 16 + tb - 1) / tb, tb, 0, stream>>>(x, xh, N * 16);
  k_cast_w1t<<<128, tb, 0, stream>>>(w1, w1t);
  k_deg<<<(E + tb - 1) / tb, tb, 0, stream>>>(edst, deg_i, rank, E);
  int nb = (N + 1023) / 1024;
  k_scan1<<<nb, 1024, 0, stream>>>(deg_i, offs, bsum, N);
  k_scan2<<<1, 64, 0, stream>>>(bsum, bofs, nb);
  k_scan3<<<(N + tb - 1) / tb, tb, 0, stream>>>(offs, bofs, deg_i, dinv, N);
  k_place<<<(E + tb - 1) / tb, tb, 0, stream>>>(esrc, edst, rank, offs, csr, E);
  k_agg<<<(N + 3) / 4, 256, 0, stream>>>(xh, csr, offs, deg_i, dinv, yh, N);
  k_gemmpool<<<(N + GN - 1) / GN, 256, 0, stream>>>(yh, w1t, b1, batch, pooled, N);
  k_head<<<N_GRAPHS, 256, 0, stream>>>(pooled, batch, N, w2, b2, w3, b3, out);
}

// Round 10
// 153.943 us; speedup vs baseline: 1.3393x; 1.0315x over previous
//
#include <hip/hip_runtime.h>

#define IN_CH   128
#define HIDDEN  256
#define N_GRAPHS 64
#define GN 64  // nodes per gemm block

typedef short short8 __attribute__((ext_vector_type(8)));
typedef float f32x4 __attribute__((ext_vector_type(4)));

__device__ inline unsigned f2bf(float f) {
  unsigned u = __float_as_uint(f);
  return (u + 0x7fffu + ((u >> 16) & 1u)) >> 16;
}
__device__ inline unsigned pack2(float lo, float hi) {
  return (f2bf(hi) << 16) | f2bf(lo);
}
__device__ inline void acc8(uint4 v, float w, float* A) {
  A[0] += w * __uint_as_float(v.x << 16);
  A[1] += w * __uint_as_float(v.x & 0xffff0000u);
  A[2] += w * __uint_as_float(v.y << 16);
  A[3] += w * __uint_as_float(v.y & 0xffff0000u);
  A[4] += w * __uint_as_float(v.z << 16);
  A[5] += w * __uint_as_float(v.z & 0xffff0000u);
  A[6] += w * __uint_as_float(v.w << 16);
  A[7] += w * __uint_as_float(v.w & 0xffff0000u);
}

// Fused preprocessing: x->bf16 cast, w1->bf16 transpose, deg count + edge rank.
__global__ void k_pre(const float* __restrict__ x, ushort* __restrict__ xh,
                      const float* __restrict__ w1, ushort* __restrict__ w1t,
                      const int* __restrict__ dst, int* __restrict__ deg,
                      int* __restrict__ rank, int total8, int e) {
  int i = blockIdx.x * blockDim.x + threadIdx.x;
  if (i < total8) {
    const float4* xp = reinterpret_cast<const float4*>(x) + (size_t)i * 2;
    float4 a = xp[0], b = xp[1];
    uint4 o;
    o.x = pack2(a.x, a.y);
    o.y = pack2(a.z, a.w);
    o.z = pack2(b.x, b.y);
    o.w = pack2(b.z, b.w);
    reinterpret_cast<uint4*>(xh)[i] = o;
  }
  if (i < HIDDEN * IN_CH) {
    int nn = i >> 7, k = i & 127;
    w1t[i] = (ushort)f2bf(w1[k * 256 + nn]);
  }
  if (i < e) {
    rank[i] = atomicAdd(&deg[dst[i]], 1);
  }
}

__global__ __launch_bounds__(1024) void k_scan1(const int* __restrict__ deg,
    int* __restrict__ offs, int* __restrict__ bsum, int n) {
  __shared__ int sm[1024];
  int t = threadIdx.x;
  int i = blockIdx.x * 1024 + t;
  int v = (i < n) ? deg[i] : 0;
  sm[t] = v;
  __syncthreads();
  for (int d = 1; d < 1024; d <<= 1) {
    int add = (t >= d) ? sm[t - d] : 0;
    __syncthreads();
    sm[t] += add;
    __syncthreads();
  }
  if (i < n) offs[i] = sm[t] - v;  // exclusive
  if (t == 1023) bsum[blockIdx.x] = sm[1023];
}

// Fused scan2+scan3: wave 0 redundantly shfl-scans block sums (nb<=64),
// then all threads apply block offset + compute dinv.
__global__ void k_scan23(int* __restrict__ offs, const int* __restrict__ bsum,
                         const int* __restrict__ deg, float* __restrict__ dinv,
                         int n, int nb) {
  __shared__ int bofs_s[64];
  int t = threadIdx.x;
  if (t < 64) {
    int orig = (t < nb) ? bsum[t] : 0;
    int v = orig;
    for (int d = 1; d < 64; d <<= 1) {
      int u = __shfl_up(v, d, 64);
      if (t >= d) v += u;
    }
    bofs_s[t] = v - orig;  // exclusive
  }
  __syncthreads();
  int i = blockIdx.x * blockDim.x + t;
  if (i < n) {
    offs[i] += bofs_s[i >> 10];
    dinv[i] = 1.0f / sqrtf((float)(deg[i] + 1));
  }
}

// atomic-free CSR fill using precomputed ranks
__global__ void k_place(const int* __restrict__ src, const int* __restrict__ dst,
                        const int* __restrict__ rank, const int* __restrict__ offs,
                        int* __restrict__ csr, int e) {
  int i = blockIdx.x * blockDim.x + threadIdx.x;
  if (i < e) csr[offs[dst[i]] + rank[i]] = src[i];
}

// 4 nodes/block. lane = es*16+cg; es = edge slot (4), cg = channel group
// (16 x 8 bf16 = 16B). 4-deep predicated slots -> 16 gather rows in flight.
__global__ __launch_bounds__(256) void k_agg(const ushort* __restrict__ xh,
    const int* __restrict__ csr, const int* __restrict__ offs,
    const int* __restrict__ degc, const float* __restrict__ dinv,
    ushort* __restrict__ yh, int n) {
  int node = blockIdx.x * 4 + (threadIdx.x >> 6);
  if (node >= n) return;
  int lane = threadIdx.x & 63;
  int es = lane >> 4;
  int cg = lane & 15;
  int o = offs[node], c = degc[node];
  float A[8] = {0.f, 0.f, 0.f, 0.f, 0.f, 0.f, 0.f, 0.f};
  for (int it = 0; it < c; it += 16) {
    float w[4];
    uint4 v[4];
#pragma unroll
    for (int u = 0; u < 4; ++u) {
      int ii = it + u * 4 + es;
      bool val = ii < c;
      int s = val ? csr[o + ii] : node;   // junk slot -> own row (cache hit)
      w[u] = val ? dinv[s] : 0.f;
      v[u] = *reinterpret_cast<const uint4*>(&xh[(size_t)s * IN_CH + cg * 8]);
    }
#pragma unroll
    for (int u = 0; u < 4; ++u) acc8(v[u], w[u], A);
  }
#pragma unroll
  for (int k = 0; k < 8; ++k) {
    A[k] += __shfl_xor(A[k], 16, 64);
    A[k] += __shfl_xor(A[k], 32, 64);
  }
  if (es == 0) {
    float dn = dinv[node];
    uint4 xs = *reinterpret_cast<const uint4*>(&xh[(size_t)node * IN_CH + cg * 8]);
    float xv[8] = {0.f, 0.f, 0.f, 0.f, 0.f, 0.f, 0.f, 0.f};
    acc8(xs, dn, xv);  // xv = x_self * dn
    float v[8];
#pragma unroll
    for (int k = 0; k < 8; ++k) v[k] = (A[k] + xv[k]) * dn;
    uint4 w;
    w.x = pack2(v[0], v[1]);
    w.y = pack2(v[2], v[3]);
    w.z = pack2(v[4], v[5]);
    w.w = pack2(v[6], v[7]);
    *reinterpret_cast<uint4*>(&yh[(size_t)node * IN_CH + cg * 8]) = w;
  }
}

// MFMA GEMM(128->256 bf16)+bias+relu fused with per-graph pooling.
// 256 threads = 4 waves; wave w owns hidden cols [w*64, w*64+64).
// Per wave: 4x4 tiles of 16x16, K = 4 chunks of 32. No operand LDS.
__global__ __launch_bounds__(256) void k_gemmpool(
    const ushort* __restrict__ yh, const ushort* __restrict__ w1t,
    const float* __restrict__ b1, const int* __restrict__ batch,
    float* __restrict__ pooled, int n) {
  __shared__ float part[4][HIDDEN];  // 4 KB
  __shared__ int bl[GN];
  int t = threadIdx.x;
  int node0 = blockIdx.x * GN;

  if (t < GN) {
    int nd = node0 + t;
    bl[t] = (nd < n) ? batch[nd] : -1;
  }
  {
    float* pp = &part[0][0];
    for (int i = t; i < 4 * HIDDEN; i += 256) pp[i] = 0.f;
  }

  int wv = t >> 6, l = t & 63;
  int lr = l & 15;   // A-row / B-col / D-col index within tile
  int lk = l >> 4;   // k-slot (A/B), row-group (D)
  int colbase = wv * 64;

  f32x4 acc[4][4];
#pragma unroll
  for (int m = 0; m < 4; ++m)
#pragma unroll
    for (int nn = 0; nn < 4; ++nn) acc[m][nn] = (f32x4){0.f, 0.f, 0.f, 0.f};

#pragma unroll
  for (int kc = 0; kc < 4; ++kc) {
    short8 a[4], b[4];
#pragma unroll
    for (int m = 0; m < 4; ++m)
      a[m] = *reinterpret_cast<const short8*>(
          &yh[(size_t)(node0 + m * 16 + lr) * IN_CH + kc * 32 + lk * 8]);
#pragma unroll
    for (int nn = 0; nn < 4; ++nn)
      b[nn] = *reinterpret_cast<const short8*>(
          &w1t[(size_t)(colbase + nn * 16 + lr) * IN_CH + kc * 32 + lk * 8]);
#pragma unroll
    for (int m = 0; m < 4; ++m)
#pragma unroll
      for (int nn = 0; nn < 4; ++nn)
        acc[m][nn] = __builtin_amdgcn_mfma_f32_16x16x32_bf16(a[m], b[nn], acc[m][nn], 0, 0, 0);
  }

  __syncthreads();  // bl + part ready; mfma results in regs

  float bias[4];
#pragma unroll
  for (int nn = 0; nn < 4; ++nn) bias[nn] = b1[colbase + nn * 16 + lr];
  int g0 = bl[0];

#pragma unroll
  for (int m = 0; m < 4; ++m) {
    float s[4] = {0.f, 0.f, 0.f, 0.f};
    int gcur = -1;
#pragma unroll
    for (int j = 0; j < 4; ++j) {
      int row = m * 16 + lk * 4 + j;
      int node = node0 + row;
      int g = (node < n) ? bl[row] : -1;
      if (g != gcur) {
        if (gcur >= 0) {
          int gi = gcur - g0;
          if (gi < 4) {
#pragma unroll
            for (int nn = 0; nn < 4; ++nn)
              atomicAdd(&part[gi][colbase + nn * 16 + lr], s[nn]);
          } else {
#pragma unroll
            for (int nn = 0; nn < 4; ++nn)
              atomicAdd(&pooled[gcur * HIDDEN + colbase + nn * 16 + lr], s[nn]);
          }
        }
#pragma unroll
        for (int u = 0; u < 4; ++u) s[u] = 0.f;
        gcur = g;
      }
      if (g >= 0) {
#pragma unroll
        for (int nn = 0; nn < 4; ++nn)
          s[nn] += fmaxf(acc[m][nn][j] + bias[nn], 0.f);
      }
    }
    if (gcur >= 0) {
      int gi = gcur - g0;
      if (gi < 4) {
#pragma unroll
        for (int nn = 0; nn < 4; ++nn)
          atomicAdd(&part[gi][colbase + nn * 16 + lr], s[nn]);
      } else {
#pragma unroll
        for (int nn = 0; nn < 4; ++nn)
          atomicAdd(&pooled[gcur * HIDDEN + colbase + nn * 16 + lr], s[nn]);
      }
    }
  }

  __syncthreads();
  int lastIdx = min(GN, n - node0) - 1;
  int gmax = bl[lastIdx];
  int span = gmax - g0;
  if (span > 3) span = 3;
  for (int gi = 0; gi <= span; ++gi) {
    atomicAdd(&pooled[(g0 + gi) * HIDDEN + t], part[gi][t]);
  }
}

// One block per graph: cnt via binary search (batch sorted), mean,
// z = relu(p@w2+b2), out = z@w3+b3  (all fp32)
__global__ __launch_bounds__(256) void k_head(const float* __restrict__ pooled,
    const int* __restrict__ batch, int n, const float* __restrict__ w2,
    const float* __restrict__ b2, const float* __restrict__ w3,
    const float* __restrict__ b3, float* __restrict__ out) {
  __shared__ float p[256];
  __shared__ float red[4];
  __shared__ int scnt;
  int g = blockIdx.x, t = threadIdx.x;
  if (t == 0) {
    int lo = 0, hi = n;
    while (lo < hi) { int mid = (lo + hi) >> 1; if (batch[mid] < g) lo = mid + 1; else hi = mid; }
    int a = lo;
    lo = 0; hi = n;
    int g1 = g + 1;
    while (lo < hi) { int mid = (lo + hi) >> 1; if (batch[mid] < g1) lo = mid + 1; else hi = mid; }
    scnt = lo - a;
  }
  __syncthreads();
  float c = (float)max(scnt, 1);
  p[t] = pooled[g * HIDDEN + t] / c;
  __syncthreads();
  float a = 0.f;
  for (int k = 0; k < 256; ++k) a += p[k] * w2[k * 256 + t];
  a += b2[t];
  a = fmaxf(a, 0.f);
  float part = a * w3[t];
  for (int off = 32; off > 0; off >>= 1) part += __shfl_down(part, off, 64);
  if ((t & 63) == 0) red[t >> 6] = part;
  __syncthreads();
  if (t == 0) out[g] = red[0] + red[1] + red[2] + red[3] + b3[0];
}

extern "C" void kernel_launch(void* const* d_in, const int* in_sizes, int n_in,
                              void* d_out, int out_size, void* d_ws, size_t ws_size,
                              hipStream_t stream) {
  const float* x    = (const float*)d_in[0];
  const int*   ei   = (const int*)d_in[1];
  const int*   batch= (const int*)d_in[2];
  const float* w1   = (const float*)d_in[3];
  const float* b1   = (const float*)d_in[4];
  const float* w2   = (const float*)d_in[5];
  const float* b2   = (const float*)d_in[6];
  const float* w3   = (const float*)d_in[7];
  const float* b3   = (const float*)d_in[8];
  float* out = (float*)d_out;

  int N = in_sizes[2];
  int E = in_sizes[1] / 2;
  const int* esrc = ei;
  const int* edst = ei + E;
  int NP = ((N + 63) / 64) * 64;  // padded rows for yh
  (void)NP;

  // layout (ints): [deg_i N][pooled 16384] (one zero-fill) [offs N][dinv N]
  // [bsum 64][rank E][csr E][w1t 16384][xh N*64][yh NP*64]
  int* W = (int*)d_ws;
  int*    deg_i  = W;
  float*  pooled = (float*)(W + N);
  int*    offs   = W + N + N_GRAPHS * HIDDEN;
  float*  dinv   = (float*)(offs + N);
  int*    bsum   = (int*)(dinv + N);
  int*    rank   = bsum + 64;
  int*    csr    = rank + E;
  ushort* w1t    = (ushort*)(csr + E);
  ushort* xh     = (ushort*)(csr + E + 16384);
  ushort* yh     = xh + (size_t)N * IN_CH;

  hipMemsetAsync(deg_i, 0, (size_t)(N + N_GRAPHS * HIDDEN) * sizeof(int), stream);

  const int tb = 256;
  int total8 = N * 16;
  int preN = max(total8, E);
  k_pre<<<(preN + tb - 1) / tb, tb, 0, stream>>>(x, xh, w1, w1t, edst, deg_i, rank, total8, E);
  int nb = (N + 1023) / 1024;
  k_scan1<<<nb, 1024, 0, stream>>>(deg_i, offs, bsum, N);
  k_scan23<<<(N + tb - 1) / tb, tb, 0, stream>>>(offs, bsum, deg_i, dinv, N, nb);
  k_place<<<(E + tb - 1) / tb, tb, 0, stream>>>(esrc, edst, rank, offs, csr, E);
  k_agg<<<(N + 3) / 4, 256, 0, stream>>>(xh, csr, offs, deg_i, dinv, yh, N);
  k_gemmpool<<<(N + GN - 1) / GN, 256, 0, stream>>>(yh, w1t, b1, batch, pooled, N);
  k_head<<<N_GRAPHS, 256, 0, stream>>>(pooled, batch, N, w2, b2, w3, b3, out);
}